// Round 1
// baseline (425.906 us; speedup 1.0000x reference)
//
#include <hip/hip_runtime.h>
#include <hip/hip_bf16.h>

// Problem constants: B=8, S=1024, D=768, H=12, DH=64
#define BB 8
#define SS 1024
#define DD 768
#define HH 12
#define DHH 64

typedef __attribute__((ext_vector_type(8))) _Float16 f16x8;
typedef __attribute__((ext_vector_type(4))) _Float16 f16x4;
typedef __attribute__((ext_vector_type(4))) float f32x4;

// ---------------------------------------------------------------------------
// Kernel 1: fp32 -> fp16 conversion of X and W (concat Wq|Wk|Wv), bias concat
// ---------------------------------------------------------------------------
__global__ void prep_kernel(const float* __restrict__ X,
                            const float* __restrict__ Wq,
                            const float* __restrict__ Wk,
                            const float* __restrict__ Wv,
                            const float* __restrict__ bq,
                            const float* __restrict__ bk,
                            const float* __restrict__ bv,
                            _Float16* __restrict__ Xh,
                            _Float16* __restrict__ Wh,
                            float* __restrict__ bias) {
    const int NX4 = (BB * SS * DD) / 4;   // 1572864
    const int NW4 = (DD * DD) / 4;        // 147456
    const int tid = blockIdx.x * blockDim.x + threadIdx.x;
    const int nth = gridDim.x * blockDim.x;

    for (int i = tid; i < NX4; i += nth) {
        f32x4 x = ((const f32x4*)X)[i];
        f16x4 h;
        for (int j = 0; j < 4; ++j) h[j] = (_Float16)x[j];
        ((f16x4*)Xh)[i] = h;
    }
    const float* Ws[3] = {Wq, Wk, Wv};
    for (int p = 0; p < 3; ++p) {
        const f32x4* src = (const f32x4*)Ws[p];
        f16x4* dst = (f16x4*)(Wh + (size_t)p * DD * DD);
        for (int i = tid; i < NW4; i += nth) {
            f32x4 x = src[i];
            f16x4 h;
            for (int j = 0; j < 4; ++j) h[j] = (_Float16)x[j];
            dst[i] = h;
        }
    }
    for (int i = tid; i < 3 * DD; i += nth) {
        bias[i] = (i < DD) ? bq[i] : (i < 2 * DD ? bk[i - DD] : bv[i - 2 * DD]);
    }
}

// ---------------------------------------------------------------------------
// Kernel 2: fused QKV projection GEMM.
//   out[m][n] = sum_k X[m][k] * Wcat[n][k] + bias[n],  M=8192, N=2304, K=768
//   Epilogue scatters to fp16 Q[bh][s][dh], K[bh][s][dh], Vt[bh][dh][s].
// Block = 256 threads (4 waves), block tile 128x128, wave tile 64x64.
// mfma_f32_16x16x32_f16 fragment layouts (verified convention):
//   A: lane l, elem j -> A[l&15][(l>>4)*8 + j]
//   B: lane l, elem j -> B[(l>>4)*8 + j][l&15]
//   D: lane l, reg  r -> D[(l>>4)*4 + r][l&15]
// ---------------------------------------------------------------------------
__global__ __launch_bounds__(256) void qkv_gemm(const _Float16* __restrict__ Xh,
                                                const _Float16* __restrict__ Wh,
                                                const float* __restrict__ bias,
                                                _Float16* __restrict__ Qb,
                                                _Float16* __restrict__ Kb,
                                                _Float16* __restrict__ Vt) {
    const int l  = threadIdx.x & 63;
    const int w  = threadIdx.x >> 6;
    const int wm = w >> 1, wn = w & 1;
    const int mbase = blockIdx.x * 128 + wm * 64;
    const int nbase = blockIdx.y * 128 + wn * 64;
    const int lr = l & 15;   // A/B fragment row; D column
    const int lg = l >> 4;   // lane group

    f32x4 acc[4][4] = {};

    const _Float16* Ap = Xh + (size_t)(mbase + lr) * DD + lg * 8;
    const _Float16* Bp = Wh + (size_t)(nbase + lr) * DD + lg * 8;

    for (int kk = 0; kk < DD; kk += 32) {
        f16x8 a[4], b[4];
#pragma unroll
        for (int mi = 0; mi < 4; ++mi)
            a[mi] = *(const f16x8*)(Ap + (size_t)mi * 16 * DD + kk);
#pragma unroll
        for (int ni = 0; ni < 4; ++ni)
            b[ni] = *(const f16x8*)(Bp + (size_t)ni * 16 * DD + kk);
#pragma unroll
        for (int mi = 0; mi < 4; ++mi)
#pragma unroll
            for (int ni = 0; ni < 4; ++ni)
                acc[mi][ni] = __builtin_amdgcn_mfma_f32_16x16x32_f16(
                    a[mi], b[ni], acc[mi][ni], 0, 0, 0);
    }

    // Epilogue: bias add, fp16 convert, scatter into Q / K / V^T
#pragma unroll
    for (int ni = 0; ni < 4; ++ni) {
        const int n = nbase + ni * 16 + lr;
        const float bv_ = bias[n];
        const int proj = (n >= 2 * DD) ? 2 : (n >= DD ? 1 : 0);
        const int rem = n - proj * DD;
        const int h = rem >> 6, dh = rem & 63;
#pragma unroll
        for (int mi = 0; mi < 4; ++mi) {
            const int m0 = mbase + mi * 16 + lg * 4;   // rows m0..m0+3 (reg r)
            const int b_ = m0 >> 10;
            const int s0 = m0 & 1023;
            const int bh = b_ * HH + h;
            f32x4 v = acc[mi][ni];
            if (proj == 2) {
                // V^T: [bh][dh][s], s consecutive across regs -> 8B store
                f16x4 pk;
#pragma unroll
                for (int r = 0; r < 4; ++r) pk[r] = (_Float16)(v[r] + bv_);
                *(f16x4*)(Vt + ((size_t)bh * 64 + dh) * SS + s0) = pk;
            } else {
                _Float16* dst = (proj == 0) ? Qb : Kb;
#pragma unroll
                for (int r = 0; r < 4; ++r)
                    dst[((size_t)bh * SS + (s0 + r)) * 64 + dh] =
                        (_Float16)(v[r] + bv_);
            }
        }
    }
}

// ---------------------------------------------------------------------------
// Kernel 3: flash attention with click-gate.
// One wave per (b, h, 16-row q tile).  Swapped-operand QK^T: S^T = K @ Q^T so
// the per-q softmax reduction is over regs + shfl_xor(16/32).  P^T is bounced
// through a padded LDS tile to become the B-fragment of the PV mfma.
// ---------------------------------------------------------------------------
__global__ __launch_bounds__(64) void attn_kernel(const _Float16* __restrict__ Qb,
                                                  const _Float16* __restrict__ Kb,
                                                  const _Float16* __restrict__ Vt,
                                                  const float* __restrict__ click,
                                                  const float* __restrict__ mask,
                                                  float* __restrict__ out) {
    __shared__ __align__(16) _Float16 pT2[16][40];   // [q][key(32) + pad 8]

    const int l  = threadIdx.x;
    const int lr = l & 15;
    const int lg = l >> 4;
    const int qt = blockIdx.x & 63;         // which 16-row q tile
    const int bh = blockIdx.x >> 6;
    const int b_ = bh / HH, h = bh - b_ * HH;
    const int qbase = qt * 16;

    const _Float16* Qp = Qb + (size_t)bh * (SS * 64);
    const _Float16* Kp = Kb + (size_t)bh * (SS * 64);
    const _Float16* Vp = Vt + (size_t)bh * (SS * 64);
    const float* ck = click + b_ * SS;
    const float* mk = mask + b_ * SS;

    // Q fragment (B operand of QK^T): Q[q=lr][dh = f*32 + lg*8 + j]
    f16x8 qf[2];
    qf[0] = *(const f16x8*)(Qp + (size_t)(qbase + lr) * 64 + lg * 8);
    qf[1] = *(const f16x8*)(Qp + (size_t)(qbase + lr) * 64 + 32 + lg * 8);

    f32x4 o[4] = {};            // ctx^T accumulator: dh = f*16 + lg*4 + r, q = lr
    float m_run = -INFINITY, l_run = 0.f;

    for (int c = 0; c < SS / 32; ++c) {
        const int cbase = c * 32;

        // --- QK^T for two 16-key tiles (32 keys) ---
        f32x4 st[2];
#pragma unroll
        for (int t = 0; t < 2; ++t) {
            const int kb2 = cbase + t * 16;
            f16x8 kf0 = *(const f16x8*)(Kp + (size_t)(kb2 + lr) * 64 + lg * 8);
            f16x8 kf1 = *(const f16x8*)(Kp + (size_t)(kb2 + lr) * 64 + 32 + lg * 8);
            f32x4 z = {};
            z = __builtin_amdgcn_mfma_f32_16x16x32_f16(kf0, qf[0], z, 0, 0, 0);
            st[t] = __builtin_amdgcn_mfma_f32_16x16x32_f16(kf1, qf[1], z, 0, 0, 0);
        }

        // --- gate + online softmax (per q = lane column) ---
        float s[2][4];
        float tmax = -INFINITY;
#pragma unroll
        for (int t = 0; t < 2; ++t)
#pragma unroll
            for (int r = 0; r < 4; ++r) {
                const int key = cbase + t * 16 + lg * 4 + r;
                s[t][r] = st[t][r] * (0.125f * ck[key]) + mk[key];
                tmax = fmaxf(tmax, s[t][r]);
            }
        tmax = fmaxf(tmax, __shfl_xor(tmax, 16));
        tmax = fmaxf(tmax, __shfl_xor(tmax, 32));

        const float m_new = fmaxf(m_run, tmax);
        const float scale = __expf(m_run - m_new);
        float p[2][4];
        float psum = 0.f;
#pragma unroll
        for (int t = 0; t < 2; ++t)
#pragma unroll
            for (int r = 0; r < 4; ++r) {
                p[t][r] = __expf(s[t][r] - m_new);
                psum += p[t][r];
            }
        psum += __shfl_xor(psum, 16);
        psum += __shfl_xor(psum, 32);
        l_run = l_run * scale + psum;
        m_run = m_new;
#pragma unroll
        for (int f = 0; f < 4; ++f)
#pragma unroll
            for (int r = 0; r < 4; ++r) o[f][r] *= scale;

        // --- write P^T to LDS: pT2[q][key_local], key_local = t*16 + lg*4 + r
#pragma unroll
        for (int t = 0; t < 2; ++t) {
            f16x4 pk;
#pragma unroll
            for (int r = 0; r < 4; ++r) pk[r] = (_Float16)p[t][r];
            *(f16x4*)(&pT2[lr][t * 16 + lg * 4]) = pk;
        }
        __syncthreads();

        // --- PV: ctx^T += V^T @ P^T  (K-dim = 32 keys) ---
        f16x8 pb = *(const f16x8*)(&pT2[lr][lg * 8]);   // B frag: P^T[key][q]
#pragma unroll
        for (int f = 0; f < 4; ++f) {
            f16x8 vf = *(const f16x8*)(Vp + (size_t)(f * 16 + lr) * SS + cbase + lg * 8);
            o[f] = __builtin_amdgcn_mfma_f32_16x16x32_f16(vf, pb, o[f], 0, 0, 0);
        }
        __syncthreads();   // WAR guard before next chunk's LDS writes
    }

    // --- normalize + store: out[b][s=qbase+lr][h*64 + dh], dh consecutive in r
    const float inv = 1.f / l_run;
#pragma unroll
    for (int f = 0; f < 4; ++f) {
        f32x4 v = o[f];
#pragma unroll
        for (int r = 0; r < 4; ++r) v[r] *= inv;
        float* dst = out + ((size_t)(b_ * SS + qbase + lr)) * DD + h * 64 + f * 16 + lg * 4;
        *(f32x4*)dst = v;
    }
}

// ---------------------------------------------------------------------------
// Launch
// ---------------------------------------------------------------------------
extern "C" void kernel_launch(void* const* d_in, const int* in_sizes, int n_in,
                              void* d_out, int out_size, void* d_ws, size_t ws_size,
                              hipStream_t stream) {
    const float* X     = (const float*)d_in[0];   // hidden_states [8,1024,768]
    const float* mask  = (const float*)d_in[1];   // attention_mask [8,1,1,1024]
    const float* click = (const float*)d_in[2];   // click_times [8,1024]
    const float* Wq    = (const float*)d_in[3];
    const float* bq    = (const float*)d_in[4];
    const float* Wk    = (const float*)d_in[5];
    const float* bk    = (const float*)d_in[6];
    const float* Wv    = (const float*)d_in[7];
    const float* bv    = (const float*)d_in[8];
    float* out = (float*)d_out;

    char* ws = (char*)d_ws;
    // Workspace layout (bytes):
    //   Xh  : 8192*768*2          = 12,582,912
    //   Wh  : 2304*768*2          =  3,538,944
    //   bias: 2304*4              =      9,216
    //   Qb  : 8*12*1024*64*2      = 12,582,912
    //   Kb  : same
    //   Vt  : same                -> total ~53.9 MB
    _Float16* Xh  = (_Float16*)(ws);
    _Float16* Wh  = (_Float16*)(ws + 12582912);
    float*    bia = (float*)   (ws + 16121856);
    _Float16* Qb  = (_Float16*)(ws + 16131072);
    _Float16* Kb  = (_Float16*)(ws + 28713984);
    _Float16* Vt  = (_Float16*)(ws + 41296896);

    prep_kernel<<<1024, 256, 0, stream>>>(X, Wq, Wk, Wv, bq, bk, bv, Xh, Wh, bia);
    qkv_gemm<<<dim3(64, 18), 256, 0, stream>>>(Xh, Wh, bia, Qb, Kb, Vt);
    attn_kernel<<<BB * HH * (SS / 16), 64, 0, stream>>>(Qb, Kb, Vt, click, mask, out);
}

// Round 2
// 208.063 us; speedup vs baseline: 2.0470x; 2.0470x over previous
//
#include <hip/hip_runtime.h>
#include <hip/hip_bf16.h>

// Problem constants: B=8, S=1024, D=768, H=12, DH=64
#define BB 8
#define SS 1024
#define DD 768
#define HH 12

typedef __attribute__((ext_vector_type(8))) _Float16 f16x8;
typedef __attribute__((ext_vector_type(4))) _Float16 f16x4;
typedef __attribute__((ext_vector_type(4))) float f32x4;

typedef __attribute__((address_space(3))) void lds_void;
typedef const __attribute__((address_space(1))) void gmem_void;
#define GLOAD_LDS16(src, dst) \
    __builtin_amdgcn_global_load_lds((gmem_void*)(src), (lds_void*)(dst), 16, 0, 0)

// ---------------------------------------------------------------------------
// Kernel 1: fp32 -> fp16 conversion of X and W (concat Wq|Wk|Wv), bias concat
// ---------------------------------------------------------------------------
__global__ void prep_kernel(const float* __restrict__ X,
                            const float* __restrict__ Wq,
                            const float* __restrict__ Wk,
                            const float* __restrict__ Wv,
                            const float* __restrict__ bq,
                            const float* __restrict__ bk,
                            const float* __restrict__ bv,
                            _Float16* __restrict__ Xh,
                            _Float16* __restrict__ Wh,
                            float* __restrict__ bias) {
    const int NX4 = (BB * SS * DD) / 4;
    const int NW4 = (DD * DD) / 4;
    const int tid = blockIdx.x * blockDim.x + threadIdx.x;
    const int nth = gridDim.x * blockDim.x;

    for (int i = tid; i < NX4; i += nth) {
        f32x4 x = ((const f32x4*)X)[i];
        f16x4 h;
        for (int j = 0; j < 4; ++j) h[j] = (_Float16)x[j];
        ((f16x4*)Xh)[i] = h;
    }
    const float* Ws[3] = {Wq, Wk, Wv};
    for (int p = 0; p < 3; ++p) {
        const f32x4* src = (const f32x4*)Ws[p];
        f16x4* dst = (f16x4*)(Wh + (size_t)p * DD * DD);
        for (int i = tid; i < NW4; i += nth) {
            f32x4 x = src[i];
            f16x4 h;
            for (int j = 0; j < 4; ++j) h[j] = (_Float16)x[j];
            dst[i] = h;
        }
    }
    for (int i = tid; i < 3 * DD; i += nth) {
        bias[i] = (i < DD) ? bq[i] : (i < 2 * DD ? bk[i - DD] : bv[i - 2 * DD]);
    }
}

// ---------------------------------------------------------------------------
// Kernel 2: fused QKV GEMM, m97 structure.
//   M=8192, N=2304, K=768. Block 256 thr (4 waves, 2x2), tile 128x128, BK=32.
//   LDS double-buffered A/B tiles staged via global_load_lds(16B); the global
//   SOURCE is pre-swizzled (cb ^= ((row>>1)&3)<<4) so swizzled ds_read_b128
//   frag loads are 2-way-conflict (free); LDS dest stays linear (rule #21).
// Fragment conventions (verified R0): A: l,j -> A[l&15][lg*8+j];
//   B: l,j -> B[lg*8+j][l&15]; D: l,r -> D[lg*4+r][l&15].
// ---------------------------------------------------------------------------
__global__ __launch_bounds__(256, 3) void qkv_gemm(const _Float16* __restrict__ Xh,
                                                   const _Float16* __restrict__ Wh,
                                                   const float* __restrict__ bias,
                                                   _Float16* __restrict__ Qb,
                                                   _Float16* __restrict__ Kb,
                                                   _Float16* __restrict__ Vt) {
    __shared__ __align__(16) _Float16 At[2][128 * 32];
    __shared__ __align__(16) _Float16 Bt[2][128 * 32];

    const int tid = threadIdx.x;
    const int l = tid & 63, w = tid >> 6;
    const int wm = w >> 1, wn = w & 1;
    const int mblk = blockIdx.x * 128, nblk = blockIdx.y * 128;
    const int lr = l & 15, lg = l >> 4;
    const int mbase = mblk + wm * 64, nbase = nblk + wn * 64;

    // --- staging geometry: issue i in {0,1}; lane covers tile row
    //     w*32 + i*16 + (l>>2), phys byte col (l&3)*16.
    const int sr_i = l >> 2;            // 0..15
    const int scb  = (l & 3) << 4;      // 0,16,32,48
    const int sx   = (sr_i >> 1) & 3;   // swizzle bits (row>>1)&3 (lane-const)
    const int scol = (scb ^ (sx << 4)) >> 1;  // logical fp16 col 0,8,16,24

    const _Float16* Ag = Xh + (size_t)(mblk + w * 32 + sr_i) * DD + scol;
    const _Float16* Bg = Wh + (size_t)(nblk + w * 32 + sr_i) * DD + scol;

    // --- compute-side frag offsets (swizzled read)
    const int ax = (lr >> 1) & 3;
    const int acol = (lg ^ ax) << 3;                   // element col within 32
    const int arow0 = (wm * 64 + lr) * 32 + acol;
    const int brow0 = (wn * 64 + lr) * 32 + acol;

    f32x4 acc[4][4] = {};

    // prologue: stage K-step 0 into buf 0
#pragma unroll
    for (int i = 0; i < 2; ++i) {
        GLOAD_LDS16(Ag + i * 16 * DD, &At[0][w * 1024 + i * 512]);
        GLOAD_LDS16(Bg + i * 16 * DD, &Bt[0][w * 1024 + i * 512]);
    }
    __syncthreads();

    for (int s_ = 0; s_ < 24; ++s_) {
        const int cur = s_ & 1;
        if (s_ < 23) {
            const int kk = (s_ + 1) * 32;
#pragma unroll
            for (int i = 0; i < 2; ++i) {
                GLOAD_LDS16(Ag + kk + i * 16 * DD, &At[cur ^ 1][w * 1024 + i * 512]);
                GLOAD_LDS16(Bg + kk + i * 16 * DD, &Bt[cur ^ 1][w * 1024 + i * 512]);
            }
        }
        f16x8 a[4], b[4];
#pragma unroll
        for (int mi = 0; mi < 4; ++mi)
            a[mi] = *(const f16x8*)(&At[cur][arow0 + mi * 512]);
#pragma unroll
        for (int ni = 0; ni < 4; ++ni)
            b[ni] = *(const f16x8*)(&Bt[cur][brow0 + ni * 512]);
        __builtin_amdgcn_s_setprio(1);
#pragma unroll
        for (int mi = 0; mi < 4; ++mi)
#pragma unroll
            for (int ni = 0; ni < 4; ++ni)
                acc[mi][ni] = __builtin_amdgcn_mfma_f32_16x16x32_f16(
                    a[mi], b[ni], acc[mi][ni], 0, 0, 0);
        __builtin_amdgcn_s_setprio(0);
        __syncthreads();   // drains this iter's staging loads (vmcnt 0) + sync
    }

    // Epilogue: bias add, fp16 convert, scatter into Q / K / V^T
#pragma unroll
    for (int ni = 0; ni < 4; ++ni) {
        const int n = nbase + ni * 16 + lr;
        const float bv_ = bias[n];
        const int proj = (n >= 2 * DD) ? 2 : (n >= DD ? 1 : 0);
        const int rem = n - proj * DD;
        const int h = rem >> 6, dh = rem & 63;
#pragma unroll
        for (int mi = 0; mi < 4; ++mi) {
            const int m0 = mbase + mi * 16 + lg * 4;
            const int b_ = m0 >> 10;
            const int s0 = m0 & 1023;
            const int bh = b_ * HH + h;
            f32x4 v = acc[mi][ni];
            if (proj == 2) {
                f16x4 pk;
#pragma unroll
                for (int r = 0; r < 4; ++r) pk[r] = (_Float16)(v[r] + bv_);
                *(f16x4*)(Vt + ((size_t)bh * 64 + dh) * SS + s0) = pk;
            } else {
                _Float16* dst = (proj == 0) ? Qb : Kb;
#pragma unroll
                for (int r = 0; r < 4; ++r)
                    dst[((size_t)bh * SS + (s0 + r)) * 64 + dh] =
                        (_Float16)(v[r] + bv_);
            }
        }
    }
}

// ---------------------------------------------------------------------------
// Kernel 3: flash attention, 4-wave blocks, LDS-shared double-buffered K/V.
//   Block owns 64 q rows (wave w -> rows qt*64 + w*16); 16 chunks of 64 keys.
//   K[64][64] and V^T[64][64] fp16 tiles staged via global_load_lds with
//   source pre-swizzle (cb ^= (row&7)<<4) -> conflict-free swizzled reads.
//   Swapped-operand QK^T, in-register online softmax with defer-max (T13),
//   wave-private P^T bounce (no block barrier), setprio around MFMA (T5).
// ---------------------------------------------------------------------------
__global__ __launch_bounds__(256, 4) void attn_kernel(const _Float16* __restrict__ Qb,
                                                      const _Float16* __restrict__ Kb,
                                                      const _Float16* __restrict__ Vt,
                                                      const float* __restrict__ click,
                                                      const float* __restrict__ mask,
                                                      float* __restrict__ out) {
    __shared__ __align__(16) _Float16 Ksh[2][64 * 64];
    __shared__ __align__(16) _Float16 Vsh[2][64 * 64];
    __shared__ __align__(16) _Float16 pT[4][16][40];   // per-wave, 32 keys + pad

    const int tid = threadIdx.x;
    const int l = tid & 63, w = tid >> 6;
    const int lr = l & 15, lg = l >> 4;
    const int qt = blockIdx.x & 15;
    const int bh = blockIdx.x >> 4;
    const int b_ = bh / HH, h = bh - b_ * HH;
    const int qbase = qt * 64 + w * 16;

    const _Float16* Qp = Qb + (size_t)bh * (SS * 64);
    const _Float16* Kp = Kb + (size_t)bh * (SS * 64);
    const _Float16* Vp = Vt + (size_t)bh * (SS * 64);
    const float* ck = click + b_ * SS;
    const float* mk = mask + b_ * SS;

    const f16x8 qf0 = *(const f16x8*)(Qp + (size_t)(qbase + lr) * 64 + lg * 8);
    const f16x8 qf1 = *(const f16x8*)(Qp + (size_t)(qbase + lr) * 64 + 32 + lg * 8);

    // staging geometry: row (0..63) = w*16 + i*8 + (l>>3); phys cb = (l&7)*16
    const int srow = l >> 3;
    const int scb  = (l & 7) << 4;
    const int scol = (scb ^ (srow << 4)) >> 1;   // pre-swizzled logical fp16 col
    const _Float16* Kg = Kp + (size_t)(w * 16 + srow) * 64 + scol;  // +(cb+i*8)*64
    const _Float16* Vg = Vp + (size_t)(w * 16 + srow) * SS + scol;  // +cb +i*8*SS

    // prologue: stage chunk 0 into buf 0
#pragma unroll
    for (int i = 0; i < 2; ++i) {
        GLOAD_LDS16(Kg + (size_t)(i * 8) * 64, &Ksh[0][w * 1024 + i * 512]);
        GLOAD_LDS16(Vg + (size_t)(i * 8) * SS, &Vsh[0][w * 1024 + i * 512]);
    }
    __syncthreads();

    f32x4 o[4] = {};
    float m_run = -3.0e38f, l_run = 0.f;
    const int sw = (lr & 7) << 4;

    for (int c = 0; c < 16; ++c) {
        const int cur = c & 1;
        if (c < 15) {   // issue next chunk; stays in flight under compute
            const int nb = (c + 1) * 64;
#pragma unroll
            for (int i = 0; i < 2; ++i) {
                GLOAD_LDS16(Kg + (size_t)(nb + i * 8) * 64, &Ksh[cur ^ 1][w * 1024 + i * 512]);
                GLOAD_LDS16(Vg + nb + (size_t)(i * 8) * SS, &Vsh[cur ^ 1][w * 1024 + i * 512]);
            }
        }
        const _Float16* Ks = Ksh[cur];
        const _Float16* Vs = Vsh[cur];
        const int cb64 = c * 64;

#pragma unroll
        for (int ks = 0; ks < 2; ++ks) {
            // --- QK^T (swapped): st[t] lane l reg r = S[key=ks*32+t*16+lg*4+r][q=lr]
            f32x4 st[2];
            __builtin_amdgcn_s_setprio(1);
#pragma unroll
            for (int t = 0; t < 2; ++t) {
                const int row = (ks * 2 + t) * 16 + lr;
                const f16x8 kf0 = *(const f16x8*)(Ks + row * 64 + (((lg << 4) ^ sw) >> 1));
                const f16x8 kf1 = *(const f16x8*)(Ks + row * 64 + (((64 | (lg << 4)) ^ sw) >> 1));
                f32x4 z = {};
                z = __builtin_amdgcn_mfma_f32_16x16x32_f16(kf0, qf0, z, 0, 0, 0);
                st[t] = __builtin_amdgcn_mfma_f32_16x16x32_f16(kf1, qf1, z, 0, 0, 0);
            }
            __builtin_amdgcn_s_setprio(0);

            // --- gate + online softmax (defer-max)
            const int koff = cb64 + ks * 32 + lg * 4;
            const f32x4 ck0 = *(const f32x4*)(ck + koff);
            const f32x4 ck1 = *(const f32x4*)(ck + koff + 16);
            const f32x4 mk0 = *(const f32x4*)(mk + koff);
            const f32x4 mk1 = *(const f32x4*)(mk + koff + 16);

            float s0[4], s1[4];
            float tmax = -3.0e38f;
#pragma unroll
            for (int r = 0; r < 4; ++r) {
                s0[r] = st[0][r] * (0.125f * ck0[r]) + mk0[r];
                s1[r] = st[1][r] * (0.125f * ck1[r]) + mk1[r];
                tmax = fmaxf(tmax, fmaxf(s0[r], s1[r]));
            }
            tmax = fmaxf(tmax, __shfl_xor(tmax, 16));
            tmax = fmaxf(tmax, __shfl_xor(tmax, 32));

            if (__any(tmax - m_run > 8.f)) {       // T13: skip rescale when safe
                const float m_new = fmaxf(m_run, tmax);
                const float sc = __expf(m_run - m_new);
                l_run *= sc;
#pragma unroll
                for (int f = 0; f < 4; ++f)
#pragma unroll
                    for (int r = 0; r < 4; ++r) o[f][r] *= sc;
                m_run = m_new;
            }

            float psum = 0.f;
            f16x4 pk0, pk1;
#pragma unroll
            for (int r = 0; r < 4; ++r) {
                const float p0 = __expf(s0[r] - m_run);
                const float p1 = __expf(s1[r] - m_run);
                psum += p0 + p1;
                pk0[r] = (_Float16)p0;
                pk1[r] = (_Float16)p1;
            }
            psum += __shfl_xor(psum, 16);
            psum += __shfl_xor(psum, 32);
            l_run += psum;

            // --- P^T bounce (wave-private; DS ops in-order within wave)
            *(f16x4*)(&pT[w][lr][lg * 4]) = pk0;
            *(f16x4*)(&pT[w][lr][16 + lg * 4]) = pk1;
            const f16x8 pb = *(const f16x8*)(&pT[w][lr][lg * 8]);

            // --- PV: o[f] += V^T tile (A) x P^T (B)
            __builtin_amdgcn_s_setprio(1);
#pragma unroll
            for (int f = 0; f < 4; ++f) {
                const int vrow = f * 16 + lr;
                const f16x8 vf = *(const f16x8*)(Vs + vrow * 64 +
                                                 ((((ks << 6) | (lg << 4)) ^ sw) >> 1));
                o[f] = __builtin_amdgcn_mfma_f32_16x16x32_f16(vf, pb, o[f], 0, 0, 0);
            }
            __builtin_amdgcn_s_setprio(0);
        }
        __syncthreads();   // drain staged loads for next chunk + release buffer
    }

    // --- normalize + store ctx^T -> out[b][s][h*64+dh]
    const float inv = 1.f / l_run;
#pragma unroll
    for (int f = 0; f < 4; ++f) {
        f32x4 v = o[f];
#pragma unroll
        for (int r = 0; r < 4; ++r) v[r] *= inv;
        float* dst = out + ((size_t)(b_ * SS + qbase + lr)) * DD + h * 64 + f * 16 + lg * 4;
        *(f32x4*)dst = v;
    }
}

// ---------------------------------------------------------------------------
// Launch
// ---------------------------------------------------------------------------
extern "C" void kernel_launch(void* const* d_in, const int* in_sizes, int n_in,
                              void* d_out, int out_size, void* d_ws, size_t ws_size,
                              hipStream_t stream) {
    const float* X     = (const float*)d_in[0];
    const float* mask  = (const float*)d_in[1];
    const float* click = (const float*)d_in[2];
    const float* Wq    = (const float*)d_in[3];
    const float* bq    = (const float*)d_in[4];
    const float* Wk    = (const float*)d_in[5];
    const float* bk    = (const float*)d_in[6];
    const float* Wv    = (const float*)d_in[7];
    const float* bv    = (const float*)d_in[8];
    float* out = (float*)d_out;

    char* ws = (char*)d_ws;
    _Float16* Xh  = (_Float16*)(ws);
    _Float16* Wh  = (_Float16*)(ws + 12582912);
    float*    bia = (float*)   (ws + 16121856);
    _Float16* Qb  = (_Float16*)(ws + 16131072);
    _Float16* Kb  = (_Float16*)(ws + 28713984);
    _Float16* Vt  = (_Float16*)(ws + 41296896);

    prep_kernel<<<1024, 256, 0, stream>>>(X, Wq, Wk, Wv, bq, bk, bv, Xh, Wh, bia);
    qkv_gemm<<<dim3(64, 18), 256, 0, stream>>>(Xh, Wh, bia, Qb, Kb, Vt);
    attn_kernel<<<BB * HH * (SS / 64), 256, 0, stream>>>(Qb, Kb, Vt, click, mask, out);
}

// Round 4
// 193.966 us; speedup vs baseline: 2.1958x; 1.0727x over previous
//
#include <hip/hip_runtime.h>
#include <hip/hip_bf16.h>

// Problem constants: B=8, S=1024, D=768, H=12, DH=64
#define BB 8
#define SS 1024
#define DD 768
#define HH 12

typedef __attribute__((ext_vector_type(8))) _Float16 f16x8;
typedef __attribute__((ext_vector_type(4))) _Float16 f16x4;
typedef __attribute__((ext_vector_type(4))) float f32x4;

typedef __attribute__((address_space(3))) void lds_void;
typedef const __attribute__((address_space(1))) void gmem_void;
#define GLOAD_LDS16(src, dst) \
    __builtin_amdgcn_global_load_lds((gmem_void*)(src), (lds_void*)(dst), 16, 0, 0)

// ---------------------------------------------------------------------------
// Kernel 1: fp32 -> fp16 convert of X and W (concat Wq|Wk|Wv), bias concat,
//           pre-scaled click (0.125 * click).
// ---------------------------------------------------------------------------
__global__ void prep_kernel(const float* __restrict__ X,
                            const float* __restrict__ Wq,
                            const float* __restrict__ Wk,
                            const float* __restrict__ Wv,
                            const float* __restrict__ bq,
                            const float* __restrict__ bk,
                            const float* __restrict__ bv,
                            const float* __restrict__ click,
                            _Float16* __restrict__ Xh,
                            _Float16* __restrict__ Wh,
                            float* __restrict__ bias,
                            float* __restrict__ ckS) {
    const int NX4 = (BB * SS * DD) / 4;   // 1572864
    const int NW4 = (DD * DD) / 4;        // 147456
    const int tid = blockIdx.x * blockDim.x + threadIdx.x;
    const int nth = gridDim.x * blockDim.x;

    for (int i = tid; i < NX4; i += nth) {
        f32x4 x = ((const f32x4*)X)[i];
        f16x4 h;
        for (int j = 0; j < 4; ++j) h[j] = (_Float16)x[j];
        ((f16x4*)Xh)[i] = h;
    }
    for (int i = tid; i < 3 * NW4; i += nth) {
        const float* src = (i < NW4) ? Wq : (i < 2 * NW4 ? Wk : Wv);
        const int ii = (i < NW4) ? i : (i < 2 * NW4 ? i - NW4 : i - 2 * NW4);
        f32x4 x = ((const f32x4*)src)[ii];
        f16x4 h;
        for (int j = 0; j < 4; ++j) h[j] = (_Float16)x[j];
        ((f16x4*)Wh)[i] = h;
    }
    for (int i = tid; i < 3 * DD; i += nth) {
        bias[i] = (i < DD) ? bq[i] : (i < 2 * DD ? bk[i - DD] : bv[i - 2 * DD]);
    }
    for (int i = tid; i < BB * SS; i += nth) {
        ckS[i] = 0.125f * click[i];
    }
}

// ---------------------------------------------------------------------------
// Kernel 2: fused QKV GEMM (m97 structure), 128x128 tile, BK=32, 4 waves.
//   XCD-swizzled 1D grid; global_load_lds staging with source pre-swizzle;
//   launch_bounds(256,4) for 4 blocks/CU.
// ---------------------------------------------------------------------------
__global__ __launch_bounds__(256, 4) void qkv_gemm(const _Float16* __restrict__ Xh,
                                                   const _Float16* __restrict__ Wh,
                                                   const float* __restrict__ bias,
                                                   _Float16* __restrict__ Qb,
                                                   _Float16* __restrict__ Kb,
                                                   _Float16* __restrict__ Vt) {
    __shared__ __align__(16) _Float16 At[2][128 * 32];
    __shared__ __align__(16) _Float16 Bt[2][128 * 32];

    const int tid = threadIdx.x;
    const int l = tid & 63, w = tid >> 6;
    const int wm = w >> 1, wn = w & 1;

    // XCD-aware bijective swizzle: 1152 blocks, 144 per XCD.
    const int bid = blockIdx.x;
    const int nid = (bid & 7) * 144 + (bid >> 3);
    const int bx = nid / 18;            // m-block 0..63  (8 X panels per XCD)
    const int by = nid - bx * 18;       // n-block 0..17
    const int mblk = bx * 128, nblk = by * 128;

    const int lr = l & 15, lg = l >> 4;
    const int mbase = mblk + wm * 64, nbase = nblk + wn * 64;

    // staging: row w*32 + i*16 + (l>>2), phys byte col (l&3)*16
    const int sr_i = l >> 2;
    const int scb  = (l & 3) << 4;
    const int sx   = (sr_i >> 1) & 3;
    const int scol = (scb ^ (sx << 4)) >> 1;

    const _Float16* Ag = Xh + (size_t)(mblk + w * 32 + sr_i) * DD + scol;
    const _Float16* Bg = Wh + (size_t)(nblk + w * 32 + sr_i) * DD + scol;

    const int ax = (lr >> 1) & 3;
    const int acol = (lg ^ ax) << 3;
    const int arow0 = (wm * 64 + lr) * 32 + acol;
    const int brow0 = (wn * 64 + lr) * 32 + acol;

    f32x4 acc[4][4] = {};

#pragma unroll
    for (int i = 0; i < 2; ++i) {
        GLOAD_LDS16(Ag + i * 16 * DD, &At[0][w * 1024 + i * 512]);
        GLOAD_LDS16(Bg + i * 16 * DD, &Bt[0][w * 1024 + i * 512]);
    }
    __syncthreads();

    for (int s_ = 0; s_ < 24; ++s_) {
        const int cur = s_ & 1;
        if (s_ < 23) {
            const int kk = (s_ + 1) * 32;
#pragma unroll
            for (int i = 0; i < 2; ++i) {
                GLOAD_LDS16(Ag + kk + i * 16 * DD, &At[cur ^ 1][w * 1024 + i * 512]);
                GLOAD_LDS16(Bg + kk + i * 16 * DD, &Bt[cur ^ 1][w * 1024 + i * 512]);
            }
        }
        f16x8 a[4], b[4];
#pragma unroll
        for (int mi = 0; mi < 4; ++mi)
            a[mi] = *(const f16x8*)(&At[cur][arow0 + mi * 512]);
#pragma unroll
        for (int ni = 0; ni < 4; ++ni)
            b[ni] = *(const f16x8*)(&Bt[cur][brow0 + ni * 512]);
        __builtin_amdgcn_s_setprio(1);
#pragma unroll
        for (int mi = 0; mi < 4; ++mi)
#pragma unroll
            for (int ni = 0; ni < 4; ++ni)
                acc[mi][ni] = __builtin_amdgcn_mfma_f32_16x16x32_f16(
                    a[mi], b[ni], acc[mi][ni], 0, 0, 0);
        __builtin_amdgcn_s_setprio(0);
        __syncthreads();
    }

    // Epilogue: bias add, fp16 convert, scatter into Q / K / V^T
#pragma unroll
    for (int ni = 0; ni < 4; ++ni) {
        const int n = nbase + ni * 16 + lr;
        const float bv_ = bias[n];
        const int proj = (n >= 2 * DD) ? 2 : (n >= DD ? 1 : 0);
        const int rem = n - proj * DD;
        const int h = rem >> 6, dh = rem & 63;
#pragma unroll
        for (int mi = 0; mi < 4; ++mi) {
            const int m0 = mbase + mi * 16 + lg * 4;
            const int b_ = m0 >> 10;
            const int s0 = m0 & 1023;
            const int bh = b_ * HH + h;
            f32x4 v = acc[mi][ni];
            if (proj == 2) {
                f16x4 pk;
#pragma unroll
                for (int r = 0; r < 4; ++r) pk[r] = (_Float16)(v[r] + bv_);
                *(f16x4*)(Vt + ((size_t)bh * 64 + dh) * SS + s0) = pk;
            } else {
                _Float16* dst = (proj == 0) ? Qb : Kb;
#pragma unroll
                for (int r = 0; r < 4; ++r)
                    dst[((size_t)bh * SS + (s0 + r)) * 64 + dh] =
                        (_Float16)(v[r] + bv_);
            }
        }
    }
}

// ---------------------------------------------------------------------------
// Kernel 3: flash attention, 4 waves/block, 2 q-tiles per wave (128 q/block).
//   K/V staged once per block, consumed by both q-sets; XCD-swizzled grid
//   groups all blocks of one bh (and 12 bh) per XCD -> K/V L2-resident.
//   768 blocks = exactly 3/CU (LDS 42 KB): single occupancy round.
// ---------------------------------------------------------------------------
__global__ __launch_bounds__(256, 3) void attn_kernel(const _Float16* __restrict__ Qb,
                                                      const _Float16* __restrict__ Kb,
                                                      const _Float16* __restrict__ Vt,
                                                      const float* __restrict__ ckS,
                                                      const float* __restrict__ mask,
                                                      float* __restrict__ out) {
    __shared__ __align__(16) _Float16 Ksh[2][64 * 64];
    __shared__ __align__(16) _Float16 Vsh[2][64 * 64];
    __shared__ __align__(16) _Float16 pT[4][2][16][40];   // per-wave, per-u

    const int tid = threadIdx.x;
    const int l = tid & 63, w = tid >> 6;
    const int lr = l & 15, lg = l >> 4;

    // XCD swizzle: 768 blocks, 96 per XCD -> 12 bh per XCD (K+V 3MB in L2)
    const int bid = blockIdx.x;
    const int nid = (bid & 7) * 96 + (bid >> 3);
    const int qt2 = nid & 7;
    const int bh  = nid >> 3;
    const int b_ = bh / HH, h = bh - b_ * HH;
    const int qb0 = qt2 * 128 + w * 16;     // u adds u*64

    const _Float16* Qp = Qb + (size_t)bh * (SS * 64);
    const _Float16* Kp = Kb + (size_t)bh * (SS * 64);
    const _Float16* Vp = Vt + (size_t)bh * (SS * 64);
    const float* ck = ckS + b_ * SS;
    const float* mk = mask + b_ * SS;

    f16x8 qf[2][2];
#pragma unroll
    for (int u = 0; u < 2; ++u) {
        qf[u][0] = *(const f16x8*)(Qp + (size_t)(qb0 + u * 64 + lr) * 64 + lg * 8);
        qf[u][1] = *(const f16x8*)(Qp + (size_t)(qb0 + u * 64 + lr) * 64 + 32 + lg * 8);
    }

    // staging geometry: row = w*16 + i*8 + (l>>3); phys byte col (l&7)*16
    const int srow = l >> 3;
    const int scb  = (l & 7) << 4;
    const int scol = (scb ^ (srow << 4)) >> 1;
    const _Float16* Kg = Kp + (size_t)(w * 16 + srow) * 64 + scol;
    const _Float16* Vg = Vp + (size_t)(w * 16 + srow) * SS + scol;

#pragma unroll
    for (int i = 0; i < 2; ++i) {
        GLOAD_LDS16(Kg + (size_t)(i * 8) * 64, &Ksh[0][w * 1024 + i * 512]);
        GLOAD_LDS16(Vg + (size_t)(i * 8) * SS, &Vsh[0][w * 1024 + i * 512]);
    }
    __syncthreads();

    f32x4 o[2][4] = {};
    float m_run[2] = {-3.0e38f, -3.0e38f};
    float l_run[2] = {0.f, 0.f};
    const int sw = (lr & 7) << 4;

    for (int c = 0; c < 16; ++c) {
        const int cur = c & 1;
        if (c < 15) {
            const int nb = (c + 1) * 64;
#pragma unroll
            for (int i = 0; i < 2; ++i) {
                GLOAD_LDS16(Kg + (size_t)(nb + i * 8) * 64, &Ksh[cur ^ 1][w * 1024 + i * 512]);
                GLOAD_LDS16(Vg + nb + (size_t)(i * 8) * SS, &Vsh[cur ^ 1][w * 1024 + i * 512]);
            }
        }
        const _Float16* Ks = Ksh[cur];
        const _Float16* Vs = Vsh[cur];
        const int cb64 = c * 64;

#pragma unroll
        for (int ks = 0; ks < 2; ++ks) {
            // --- QK^T, K-frags shared across both q-sets
            f32x4 st[2][2];
            __builtin_amdgcn_s_setprio(1);
#pragma unroll
            for (int t = 0; t < 2; ++t) {
                const int row = (ks * 2 + t) * 16 + lr;
                const f16x8 kf0 = *(const f16x8*)(Ks + row * 64 + (((lg << 4) ^ sw) >> 1));
                const f16x8 kf1 = *(const f16x8*)(Ks + row * 64 + (((64 | (lg << 4)) ^ sw) >> 1));
#pragma unroll
                for (int u = 0; u < 2; ++u) {
                    f32x4 z = {};
                    z = __builtin_amdgcn_mfma_f32_16x16x32_f16(kf0, qf[u][0], z, 0, 0, 0);
                    st[u][t] = __builtin_amdgcn_mfma_f32_16x16x32_f16(kf1, qf[u][1], z, 0, 0, 0);
                }
            }
            __builtin_amdgcn_s_setprio(0);

            const int koff = cb64 + ks * 32 + lg * 4;
            const f32x4 ck0 = *(const f32x4*)(ck + koff);
            const f32x4 ck1 = *(const f32x4*)(ck + koff + 16);
            const f32x4 mk0 = *(const f32x4*)(mk + koff);
            const f32x4 mk1 = *(const f32x4*)(mk + koff + 16);

#pragma unroll
            for (int u = 0; u < 2; ++u) {
                float s0[4], s1[4];
                float tmax = -3.0e38f;
#pragma unroll
                for (int r = 0; r < 4; ++r) {
                    s0[r] = st[u][0][r] * ck0[r] + mk0[r];
                    s1[r] = st[u][1][r] * ck1[r] + mk1[r];
                    tmax = fmaxf(tmax, fmaxf(s0[r], s1[r]));
                }
                tmax = fmaxf(tmax, __shfl_xor(tmax, 16));
                tmax = fmaxf(tmax, __shfl_xor(tmax, 32));

                if (__any(tmax - m_run[u] > 8.f)) {     // defer-max (T13)
                    const float m_new = fmaxf(m_run[u], tmax);
                    const float sc = __expf(m_run[u] - m_new);
                    l_run[u] *= sc;
#pragma unroll
                    for (int f = 0; f < 4; ++f)
#pragma unroll
                        for (int r = 0; r < 4; ++r) o[u][f][r] *= sc;
                    m_run[u] = m_new;
                }

                float psum = 0.f;
                f16x4 pk0, pk1;
#pragma unroll
                for (int r = 0; r < 4; ++r) {
                    const float p0 = __expf(s0[r] - m_run[u]);
                    const float p1 = __expf(s1[r] - m_run[u]);
                    psum += p0 + p1;
                    pk0[r] = (_Float16)p0;
                    pk1[r] = (_Float16)p1;
                }
                psum += __shfl_xor(psum, 16);
                psum += __shfl_xor(psum, 32);
                l_run[u] += psum;

                *(f16x4*)(&pT[w][u][lr][lg * 4]) = pk0;
                *(f16x4*)(&pT[w][u][lr][16 + lg * 4]) = pk1;
            }

            const f16x8 pb0 = *(const f16x8*)(&pT[w][0][lr][lg * 8]);
            const f16x8 pb1 = *(const f16x8*)(&pT[w][1][lr][lg * 8]);

            // --- PV: V-frag loaded once, feeds both q-sets
            __builtin_amdgcn_s_setprio(1);
#pragma unroll
            for (int f = 0; f < 4; ++f) {
                const int vrow = f * 16 + lr;
                const f16x8 vf = *(const f16x8*)(Vs + vrow * 64 +
                                                 ((((ks << 6) | (lg << 4)) ^ sw) >> 1));
                o[0][f] = __builtin_amdgcn_mfma_f32_16x16x32_f16(vf, pb0, o[0][f], 0, 0, 0);
                o[1][f] = __builtin_amdgcn_mfma_f32_16x16x32_f16(vf, pb1, o[1][f], 0, 0, 0);
            }
            __builtin_amdgcn_s_setprio(0);
        }
        __syncthreads();
    }

    // --- normalize + store
#pragma unroll
    for (int u = 0; u < 2; ++u) {
        const float inv = 1.f / l_run[u];
#pragma unroll
        for (int f = 0; f < 4; ++f) {
            f32x4 v = o[u][f];
#pragma unroll
            for (int r = 0; r < 4; ++r) v[r] *= inv;
            float* dst = out + ((size_t)(b_ * SS + qb0 + u * 64 + lr)) * DD +
                         h * 64 + f * 16 + lg * 4;
            *(f32x4*)dst = v;
        }
    }
}

// ---------------------------------------------------------------------------
// Launch
// ---------------------------------------------------------------------------
extern "C" void kernel_launch(void* const* d_in, const int* in_sizes, int n_in,
                              void* d_out, int out_size, void* d_ws, size_t ws_size,
                              hipStream_t stream) {
    const float* X     = (const float*)d_in[0];
    const float* mask  = (const float*)d_in[1];
    const float* click = (const float*)d_in[2];
    const float* Wq    = (const float*)d_in[3];
    const float* bq    = (const float*)d_in[4];
    const float* Wk    = (const float*)d_in[5];
    const float* bk    = (const float*)d_in[6];
    const float* Wv    = (const float*)d_in[7];
    const float* bv    = (const float*)d_in[8];
    float* out = (float*)d_out;

    char* ws = (char*)d_ws;
    _Float16* Xh  = (_Float16*)(ws);
    _Float16* Wh  = (_Float16*)(ws + 12582912);
    float*    bia = (float*)   (ws + 16121856);
    float*    ckS = (float*)   (ws + 16131072);
    _Float16* Qb  = (_Float16*)(ws + 16163840);
    _Float16* Kb  = (_Float16*)(ws + 28746752);
    _Float16* Vt  = (_Float16*)(ws + 41329664);

    prep_kernel<<<2048, 256, 0, stream>>>(X, Wq, Wk, Wv, bq, bk, bv, click,
                                          Xh, Wh, bia, ckS);
    qkv_gemm<<<1152, 256, 0, stream>>>(Xh, Wh, bia, Qb, Kb, Vt);
    attn_kernel<<<768, 256, 0, stream>>>(Qb, Kb, Vt, ckS, mask, out);
}

// Round 5
// 183.071 us; speedup vs baseline: 2.3265x; 1.0595x over previous
//
#include <hip/hip_runtime.h>
#include <hip/hip_bf16.h>

// Problem constants: B=8, S=1024, D=768, H=12, DH=64
#define BB 8
#define SS 1024
#define DD 768
#define HH 12

typedef __attribute__((ext_vector_type(8))) _Float16 f16x8;
typedef __attribute__((ext_vector_type(4))) _Float16 f16x4;
typedef __attribute__((ext_vector_type(4))) float f32x4;

typedef __attribute__((address_space(3))) void lds_void;
typedef const __attribute__((address_space(1))) void gmem_void;
#define GLOAD_LDS16(src, dst) \
    __builtin_amdgcn_global_load_lds((gmem_void*)(src), (lds_void*)(dst), 16, 0, 0)

// ---------------------------------------------------------------------------
// Kernel 1: fp32 -> fp16 convert of X and W (concat Wq|Wk|Wv), bias concat,
//           pre-scaled click (0.125 * click).
// ---------------------------------------------------------------------------
__global__ void prep_kernel(const float* __restrict__ X,
                            const float* __restrict__ Wq,
                            const float* __restrict__ Wk,
                            const float* __restrict__ Wv,
                            const float* __restrict__ bq,
                            const float* __restrict__ bk,
                            const float* __restrict__ bv,
                            const float* __restrict__ click,
                            _Float16* __restrict__ Xh,
                            _Float16* __restrict__ Wh,
                            float* __restrict__ bias,
                            float* __restrict__ ckS) {
    const int NX4 = (BB * SS * DD) / 4;   // 1572864
    const int NW4 = (DD * DD) / 4;        // 147456
    const int tid = blockIdx.x * blockDim.x + threadIdx.x;
    const int nth = gridDim.x * blockDim.x;

    for (int i = tid; i < NX4; i += nth) {
        f32x4 x = ((const f32x4*)X)[i];
        f16x4 h;
        for (int j = 0; j < 4; ++j) h[j] = (_Float16)x[j];
        ((f16x4*)Xh)[i] = h;
    }
    for (int i = tid; i < 3 * NW4; i += nth) {
        const float* src = (i < NW4) ? Wq : (i < 2 * NW4 ? Wk : Wv);
        const int ii = (i < NW4) ? i : (i < 2 * NW4 ? i - NW4 : i - 2 * NW4);
        f32x4 x = ((const f32x4*)src)[ii];
        f16x4 h;
        for (int j = 0; j < 4; ++j) h[j] = (_Float16)x[j];
        ((f16x4*)Wh)[i] = h;
    }
    for (int i = tid; i < 3 * DD; i += nth) {
        bias[i] = (i < DD) ? bq[i] : (i < 2 * DD ? bk[i - DD] : bv[i - 2 * DD]);
    }
    for (int i = tid; i < BB * SS; i += nth) {
        ckS[i] = 0.125f * click[i];
    }
}

// ---------------------------------------------------------------------------
// Kernel 2: fused QKV GEMM, 128x192 block tile, BK=32, 4 waves (wave 64x96).
//   Grid 64x12 = 768 blocks = exactly 3/CU (LDS 40 KB, <=170 VGPR): no tail.
//   24 MFMA per wave per K-step (vs 16 at 128x128): better barrier amortization.
//   global_load_lds staging, linear LDS dest + source pre-swizzle (rule #21);
//   XCD-swizzled 1D grid (768 % 8 == 0, bijective).
// ---------------------------------------------------------------------------
__global__ __launch_bounds__(256, 3) void qkv_gemm(const _Float16* __restrict__ Xh,
                                                   const _Float16* __restrict__ Wh,
                                                   const float* __restrict__ bias,
                                                   _Float16* __restrict__ Qb,
                                                   _Float16* __restrict__ Kb,
                                                   _Float16* __restrict__ Vt) {
    __shared__ __align__(16) _Float16 At[2][128 * 32];
    __shared__ __align__(16) _Float16 Bt[2][192 * 32];

    const int tid = threadIdx.x;
    const int l = tid & 63, w = tid >> 6;
    const int wm = w >> 1, wn = w & 1;

    // XCD swizzle: 768 blocks, 96 per XCD; bx = nid/12 keeps an X panel
    // (196 KB) L2-resident across its 12 n-tiles.
    const int bid = blockIdx.x;
    const int nid = (bid & 7) * 96 + (bid >> 3);
    const int bx = nid / 12;            // m-block 0..63
    const int by = nid - bx * 12;       // n-block 0..11
    const int mblk = bx * 128, nblk = by * 192;

    const int lr = l & 15, lg = l >> 4;
    const int mbase = mblk + wm * 64, nbase = nblk + wn * 96;

    // staging: within an issue, lane covers row (l>>2), phys byte col (l&3)*16
    const int sr_i = l >> 2;            // 0..15
    const int scb  = (l & 3) << 4;
    const int sx   = (sr_i >> 1) & 3;
    const int scol = (scb ^ (sx << 4)) >> 1;   // pre-swizzled fp16 col

    // A: wave w stages rows w*32 + i*16 + sr_i  (i in 0..1)
    // B: wave w stages rows w*48 + i*16 + sr_i  (i in 0..2)
    const _Float16* Ag = Xh + (size_t)(mblk + w * 32 + sr_i) * DD + scol;
    const _Float16* Bg = Wh + (size_t)(nblk + w * 48 + sr_i) * DD + scol;

    const int ax = (lr >> 1) & 3;
    const int acol = (lg ^ ax) << 3;
    const int arow0 = (wm * 64 + lr) * 32 + acol;
    const int brow0 = (wn * 96 + lr) * 32 + acol;

    f32x4 acc[4][6] = {};

#pragma unroll
    for (int i = 0; i < 2; ++i)
        GLOAD_LDS16(Ag + i * 16 * DD, &At[0][w * 1024 + i * 512]);
#pragma unroll
    for (int i = 0; i < 3; ++i)
        GLOAD_LDS16(Bg + i * 16 * DD, &Bt[0][w * 1536 + i * 512]);
    __syncthreads();

    for (int s_ = 0; s_ < 24; ++s_) {
        const int cur = s_ & 1;
        if (s_ < 23) {
            const int kk = (s_ + 1) * 32;
#pragma unroll
            for (int i = 0; i < 2; ++i)
                GLOAD_LDS16(Ag + kk + i * 16 * DD, &At[cur ^ 1][w * 1024 + i * 512]);
#pragma unroll
            for (int i = 0; i < 3; ++i)
                GLOAD_LDS16(Bg + kk + i * 16 * DD, &Bt[cur ^ 1][w * 1536 + i * 512]);
        }
        f16x8 a[4];
#pragma unroll
        for (int mi = 0; mi < 4; ++mi)
            a[mi] = *(const f16x8*)(&At[cur][arow0 + mi * 512]);
        __builtin_amdgcn_s_setprio(1);
#pragma unroll
        for (int ni = 0; ni < 6; ++ni) {
            const f16x8 b = *(const f16x8*)(&Bt[cur][brow0 + ni * 512]);
#pragma unroll
            for (int mi = 0; mi < 4; ++mi)
                acc[mi][ni] = __builtin_amdgcn_mfma_f32_16x16x32_f16(
                    a[mi], b, acc[mi][ni], 0, 0, 0);
        }
        __builtin_amdgcn_s_setprio(0);
        __syncthreads();
    }

    // Epilogue: bias add, fp16 convert, scatter into Q / K / V^T
#pragma unroll
    for (int ni = 0; ni < 6; ++ni) {
        const int n = nbase + ni * 16 + lr;
        const float bv_ = bias[n];
        const int proj = (n >= 2 * DD) ? 2 : (n >= DD ? 1 : 0);
        const int rem = n - proj * DD;
        const int h = rem >> 6, dh = rem & 63;
#pragma unroll
        for (int mi = 0; mi < 4; ++mi) {
            const int m0 = mbase + mi * 16 + lg * 4;
            const int b_ = m0 >> 10;
            const int s0 = m0 & 1023;
            const int bh = b_ * HH + h;
            f32x4 v = acc[mi][ni];
            if (proj == 2) {
                f16x4 pk;
#pragma unroll
                for (int r = 0; r < 4; ++r) pk[r] = (_Float16)(v[r] + bv_);
                *(f16x4*)(Vt + ((size_t)bh * 64 + dh) * SS + s0) = pk;
            } else {
                _Float16* dst = (proj == 0) ? Qb : Kb;
#pragma unroll
                for (int r = 0; r < 4; ++r)
                    dst[((size_t)bh * SS + (s0 + r)) * 64 + dh] =
                        (_Float16)(v[r] + bv_);
            }
        }
    }
}

// ---------------------------------------------------------------------------
// Kernel 3: flash attention, 4 waves/block, 2 q-tiles per wave (128 q/block).
//   K/V staged once per block, consumed by both q-sets; XCD-swizzled grid
//   groups all blocks of one bh (and 12 bh) per XCD -> K/V L2-resident.
//   768 blocks = exactly 3/CU (LDS 42 KB): single occupancy round.
// ---------------------------------------------------------------------------
__global__ __launch_bounds__(256, 3) void attn_kernel(const _Float16* __restrict__ Qb,
                                                      const _Float16* __restrict__ Kb,
                                                      const _Float16* __restrict__ Vt,
                                                      const float* __restrict__ ckS,
                                                      const float* __restrict__ mask,
                                                      float* __restrict__ out) {
    __shared__ __align__(16) _Float16 Ksh[2][64 * 64];
    __shared__ __align__(16) _Float16 Vsh[2][64 * 64];
    __shared__ __align__(16) _Float16 pT[4][2][16][40];   // per-wave, per-u

    const int tid = threadIdx.x;
    const int l = tid & 63, w = tid >> 6;
    const int lr = l & 15, lg = l >> 4;

    // XCD swizzle: 768 blocks, 96 per XCD -> 12 bh per XCD (K+V 3MB in L2)
    const int bid = blockIdx.x;
    const int nid = (bid & 7) * 96 + (bid >> 3);
    const int qt2 = nid & 7;
    const int bh  = nid >> 3;
    const int b_ = bh / HH, h = bh - b_ * HH;
    const int qb0 = qt2 * 128 + w * 16;     // u adds u*64

    const _Float16* Qp = Qb + (size_t)bh * (SS * 64);
    const _Float16* Kp = Kb + (size_t)bh * (SS * 64);
    const _Float16* Vp = Vt + (size_t)bh * (SS * 64);
    const float* ck = ckS + b_ * SS;
    const float* mk = mask + b_ * SS;

    f16x8 qf[2][2];
#pragma unroll
    for (int u = 0; u < 2; ++u) {
        qf[u][0] = *(const f16x8*)(Qp + (size_t)(qb0 + u * 64 + lr) * 64 + lg * 8);
        qf[u][1] = *(const f16x8*)(Qp + (size_t)(qb0 + u * 64 + lr) * 64 + 32 + lg * 8);
    }

    // staging geometry: row = w*16 + i*8 + (l>>3); phys byte col (l&7)*16
    const int srow = l >> 3;
    const int scb  = (l & 7) << 4;
    const int scol = (scb ^ (srow << 4)) >> 1;
    const _Float16* Kg = Kp + (size_t)(w * 16 + srow) * 64 + scol;
    const _Float16* Vg = Vp + (size_t)(w * 16 + srow) * SS + scol;

#pragma unroll
    for (int i = 0; i < 2; ++i) {
        GLOAD_LDS16(Kg + (size_t)(i * 8) * 64, &Ksh[0][w * 1024 + i * 512]);
        GLOAD_LDS16(Vg + (size_t)(i * 8) * SS, &Vsh[0][w * 1024 + i * 512]);
    }
    __syncthreads();

    f32x4 o[2][4] = {};
    float m_run[2] = {-3.0e38f, -3.0e38f};
    float l_run[2] = {0.f, 0.f};
    const int sw = (lr & 7) << 4;

    for (int c = 0; c < 16; ++c) {
        const int cur = c & 1;
        if (c < 15) {
            const int nb = (c + 1) * 64;
#pragma unroll
            for (int i = 0; i < 2; ++i) {
                GLOAD_LDS16(Kg + (size_t)(nb + i * 8) * 64, &Ksh[cur ^ 1][w * 1024 + i * 512]);
                GLOAD_LDS16(Vg + nb + (size_t)(i * 8) * SS, &Vsh[cur ^ 1][w * 1024 + i * 512]);
            }
        }
        const _Float16* Ks = Ksh[cur];
        const _Float16* Vs = Vsh[cur];
        const int cb64 = c * 64;

#pragma unroll
        for (int ks = 0; ks < 2; ++ks) {
            // --- QK^T, K-frags shared across both q-sets
            f32x4 st[2][2];
            __builtin_amdgcn_s_setprio(1);
#pragma unroll
            for (int t = 0; t < 2; ++t) {
                const int row = (ks * 2 + t) * 16 + lr;
                const f16x8 kf0 = *(const f16x8*)(Ks + row * 64 + (((lg << 4) ^ sw) >> 1));
                const f16x8 kf1 = *(const f16x8*)(Ks + row * 64 + (((64 | (lg << 4)) ^ sw) >> 1));
#pragma unroll
                for (int u = 0; u < 2; ++u) {
                    f32x4 z = {};
                    z = __builtin_amdgcn_mfma_f32_16x16x32_f16(kf0, qf[u][0], z, 0, 0, 0);
                    st[u][t] = __builtin_amdgcn_mfma_f32_16x16x32_f16(kf1, qf[u][1], z, 0, 0, 0);
                }
            }
            __builtin_amdgcn_s_setprio(0);

            const int koff = cb64 + ks * 32 + lg * 4;
            const f32x4 ck0 = *(const f32x4*)(ck + koff);
            const f32x4 ck1 = *(const f32x4*)(ck + koff + 16);
            const f32x4 mk0 = *(const f32x4*)(mk + koff);
            const f32x4 mk1 = *(const f32x4*)(mk + koff + 16);

#pragma unroll
            for (int u = 0; u < 2; ++u) {
                float s0[4], s1[4];
                float tmax = -3.0e38f;
#pragma unroll
                for (int r = 0; r < 4; ++r) {
                    s0[r] = st[u][0][r] * ck0[r] + mk0[r];
                    s1[r] = st[u][1][r] * ck1[r] + mk1[r];
                    tmax = fmaxf(tmax, fmaxf(s0[r], s1[r]));
                }
                tmax = fmaxf(tmax, __shfl_xor(tmax, 16));
                tmax = fmaxf(tmax, __shfl_xor(tmax, 32));

                if (__any(tmax - m_run[u] > 8.f)) {     // defer-max (T13)
                    const float m_new = fmaxf(m_run[u], tmax);
                    const float sc = __expf(m_run[u] - m_new);
                    l_run[u] *= sc;
#pragma unroll
                    for (int f = 0; f < 4; ++f)
#pragma unroll
                        for (int r = 0; r < 4; ++r) o[u][f][r] *= sc;
                    m_run[u] = m_new;
                }

                float psum = 0.f;
                f16x4 pk0, pk1;
#pragma unroll
                for (int r = 0; r < 4; ++r) {
                    const float p0 = __expf(s0[r] - m_run[u]);
                    const float p1 = __expf(s1[r] - m_run[u]);
                    psum += p0 + p1;
                    pk0[r] = (_Float16)p0;
                    pk1[r] = (_Float16)p1;
                }
                psum += __shfl_xor(psum, 16);
                psum += __shfl_xor(psum, 32);
                l_run[u] += psum;

                *(f16x4*)(&pT[w][u][lr][lg * 4]) = pk0;
                *(f16x4*)(&pT[w][u][lr][16 + lg * 4]) = pk1;
            }

            const f16x8 pb0 = *(const f16x8*)(&pT[w][0][lr][lg * 8]);
            const f16x8 pb1 = *(const f16x8*)(&pT[w][1][lr][lg * 8]);

            // --- PV: V-frag loaded once, feeds both q-sets
            __builtin_amdgcn_s_setprio(1);
#pragma unroll
            for (int f = 0; f < 4; ++f) {
                const int vrow = f * 16 + lr;
                const f16x8 vf = *(const f16x8*)(Vs + vrow * 64 +
                                                 ((((ks << 6) | (lg << 4)) ^ sw) >> 1));
                o[0][f] = __builtin_amdgcn_mfma_f32_16x16x32_f16(vf, pb0, o[0][f], 0, 0, 0);
                o[1][f] = __builtin_amdgcn_mfma_f32_16x16x32_f16(vf, pb1, o[1][f], 0, 0, 0);
            }
            __builtin_amdgcn_s_setprio(0);
        }
        __syncthreads();
    }

    // --- normalize + store
#pragma unroll
    for (int u = 0; u < 2; ++u) {
        const float inv = 1.f / l_run[u];
#pragma unroll
        for (int f = 0; f < 4; ++f) {
            f32x4 v = o[u][f];
#pragma unroll
            for (int r = 0; r < 4; ++r) v[r] *= inv;
            float* dst = out + ((size_t)(b_ * SS + qb0 + u * 64 + lr)) * DD +
                         h * 64 + f * 16 + lg * 4;
            *(f32x4*)dst = v;
        }
    }
}

// ---------------------------------------------------------------------------
// Launch
// ---------------------------------------------------------------------------
extern "C" void kernel_launch(void* const* d_in, const int* in_sizes, int n_in,
                              void* d_out, int out_size, void* d_ws, size_t ws_size,
                              hipStream_t stream) {
    const float* X     = (const float*)d_in[0];
    const float* mask  = (const float*)d_in[1];
    const float* click = (const float*)d_in[2];
    const float* Wq    = (const float*)d_in[3];
    const float* bq    = (const float*)d_in[4];
    const float* Wk    = (const float*)d_in[5];
    const float* bk    = (const float*)d_in[6];
    const float* Wv    = (const float*)d_in[7];
    const float* bv    = (const float*)d_in[8];
    float* out = (float*)d_out;

    char* ws = (char*)d_ws;
    _Float16* Xh  = (_Float16*)(ws);
    _Float16* Wh  = (_Float16*)(ws + 12582912);
    float*    bia = (float*)   (ws + 16121856);
    float*    ckS = (float*)   (ws + 16131072);
    _Float16* Qb  = (_Float16*)(ws + 16163840);
    _Float16* Kb  = (_Float16*)(ws + 28746752);
    _Float16* Vt  = (_Float16*)(ws + 41329664);

    prep_kernel<<<2048, 256, 0, stream>>>(X, Wq, Wk, Wv, bq, bk, bv, click,
                                          Xh, Wh, bia, ckS);
    qkv_gemm<<<768, 256, 0, stream>>>(Xh, Wh, bia, Qb, Kb, Vt);
    attn_kernel<<<768, 256, 0, stream>>>(Qb, Kb, Vt, ckS, mask, out);
}

// Round 7
// 181.845 us; speedup vs baseline: 2.3421x; 1.0067x over previous
//
#include <hip/hip_runtime.h>
#include <hip/hip_bf16.h>

// Problem constants: B=8, S=1024, D=768, H=12, DH=64
#define BB 8
#define SS 1024
#define DD 768
#define HH 12
#define LOG2E 1.4426950408889634f

typedef __attribute__((ext_vector_type(8))) _Float16 f16x8;
typedef __attribute__((ext_vector_type(4))) _Float16 f16x4;
typedef __attribute__((ext_vector_type(4))) float f32x4;

typedef __attribute__((address_space(3))) void lds_void;
typedef const __attribute__((address_space(1))) void gmem_void;
#define GLOAD_LDS16(src, dst) \
    __builtin_amdgcn_global_load_lds((gmem_void*)(src), (lds_void*)(dst), 16, 0, 0)

// ---------------------------------------------------------------------------
// Kernel 1: fp32 -> fp16 convert of X and W (concat Wq|Wk|Wv), bias concat,
//   click pre-scaled by 0.125*log2e and mask by log2e (exp2-domain softmax).
// ---------------------------------------------------------------------------
__global__ void prep_kernel(const float* __restrict__ X,
                            const float* __restrict__ Wq,
                            const float* __restrict__ Wk,
                            const float* __restrict__ Wv,
                            const float* __restrict__ bq,
                            const float* __restrict__ bk,
                            const float* __restrict__ bv,
                            const float* __restrict__ click,
                            const float* __restrict__ mask,
                            _Float16* __restrict__ Xh,
                            _Float16* __restrict__ Wh,
                            float* __restrict__ bias,
                            float* __restrict__ ckS,
                            float* __restrict__ mkL) {
    const int NX4 = (BB * SS * DD) / 4;   // 1572864
    const int NW4 = (DD * DD) / 4;        // 147456
    const int tid = blockIdx.x * blockDim.x + threadIdx.x;
    const int nth = gridDim.x * blockDim.x;

    for (int i = tid; i < NX4; i += nth) {
        f32x4 x = ((const f32x4*)X)[i];
        f16x4 h;
        for (int j = 0; j < 4; ++j) h[j] = (_Float16)x[j];
        ((f16x4*)Xh)[i] = h;
    }
    for (int i = tid; i < 3 * NW4; i += nth) {
        const float* src = (i < NW4) ? Wq : (i < 2 * NW4 ? Wk : Wv);
        const int ii = (i < NW4) ? i : (i < 2 * NW4 ? i - NW4 : i - 2 * NW4);
        f32x4 x = ((const f32x4*)src)[ii];
        f16x4 h;
        for (int j = 0; j < 4; ++j) h[j] = (_Float16)x[j];
        ((f16x4*)Wh)[i] = h;
    }
    for (int i = tid; i < 3 * DD; i += nth) {
        bias[i] = (i < DD) ? bq[i] : (i < 2 * DD ? bk[i - DD] : bv[i - 2 * DD]);
    }
    for (int i = tid; i < BB * SS; i += nth) {
        ckS[i] = (0.125f * LOG2E) * click[i];
        mkL[i] = LOG2E * mask[i];
    }
}

// ---------------------------------------------------------------------------
// Kernel 2: fused QKV GEMM, 128x192 block tile, BK=32, 4 waves (wave 64x96).
//   Grid 768 = exactly 3/CU; XCD-swizzled; global_load_lds + source
//   pre-swizzle (rule #21).  [unchanged from R4]
// ---------------------------------------------------------------------------
__global__ __launch_bounds__(256, 3) void qkv_gemm(const _Float16* __restrict__ Xh,
                                                   const _Float16* __restrict__ Wh,
                                                   const float* __restrict__ bias,
                                                   _Float16* __restrict__ Qb,
                                                   _Float16* __restrict__ Kb,
                                                   _Float16* __restrict__ Vt) {
    __shared__ __align__(16) _Float16 At[2][128 * 32];
    __shared__ __align__(16) _Float16 Bt[2][192 * 32];

    const int tid = threadIdx.x;
    const int l = tid & 63, w = tid >> 6;
    const int wm = w >> 1, wn = w & 1;

    const int bid = blockIdx.x;
    const int nid = (bid & 7) * 96 + (bid >> 3);
    const int bx = nid / 12;
    const int by = nid - bx * 12;
    const int mblk = bx * 128, nblk = by * 192;

    const int lr = l & 15, lg = l >> 4;
    const int mbase = mblk + wm * 64, nbase = nblk + wn * 96;

    const int sr_i = l >> 2;
    const int scb  = (l & 3) << 4;
    const int sx   = (sr_i >> 1) & 3;
    const int scol = (scb ^ (sx << 4)) >> 1;

    const _Float16* Ag = Xh + (size_t)(mblk + w * 32 + sr_i) * DD + scol;
    const _Float16* Bg = Wh + (size_t)(nblk + w * 48 + sr_i) * DD + scol;

    const int ax = (lr >> 1) & 3;
    const int acol = (lg ^ ax) << 3;
    const int arow0 = (wm * 64 + lr) * 32 + acol;
    const int brow0 = (wn * 96 + lr) * 32 + acol;

    f32x4 acc[4][6] = {};

#pragma unroll
    for (int i = 0; i < 2; ++i)
        GLOAD_LDS16(Ag + i * 16 * DD, &At[0][w * 1024 + i * 512]);
#pragma unroll
    for (int i = 0; i < 3; ++i)
        GLOAD_LDS16(Bg + i * 16 * DD, &Bt[0][w * 1536 + i * 512]);
    __syncthreads();

    for (int s_ = 0; s_ < 24; ++s_) {
        const int cur = s_ & 1;
        if (s_ < 23) {
            const int kk = (s_ + 1) * 32;
#pragma unroll
            for (int i = 0; i < 2; ++i)
                GLOAD_LDS16(Ag + kk + i * 16 * DD, &At[cur ^ 1][w * 1024 + i * 512]);
#pragma unroll
            for (int i = 0; i < 3; ++i)
                GLOAD_LDS16(Bg + kk + i * 16 * DD, &Bt[cur ^ 1][w * 1536 + i * 512]);
        }
        f16x8 a[4];
#pragma unroll
        for (int mi = 0; mi < 4; ++mi)
            a[mi] = *(const f16x8*)(&At[cur][arow0 + mi * 512]);
        __builtin_amdgcn_s_setprio(1);
#pragma unroll
        for (int ni = 0; ni < 6; ++ni) {
            const f16x8 b = *(const f16x8*)(&Bt[cur][brow0 + ni * 512]);
#pragma unroll
            for (int mi = 0; mi < 4; ++mi)
                acc[mi][ni] = __builtin_amdgcn_mfma_f32_16x16x32_f16(
                    a[mi], b, acc[mi][ni], 0, 0, 0);
        }
        __builtin_amdgcn_s_setprio(0);
        __syncthreads();
    }

#pragma unroll
    for (int ni = 0; ni < 6; ++ni) {
        const int n = nbase + ni * 16 + lr;
        const float bv_ = bias[n];
        const int proj = (n >= 2 * DD) ? 2 : (n >= DD ? 1 : 0);
        const int rem = n - proj * DD;
        const int h = rem >> 6, dh = rem & 63;
#pragma unroll
        for (int mi = 0; mi < 4; ++mi) {
            const int m0 = mbase + mi * 16 + lg * 4;
            const int b_ = m0 >> 10;
            const int s0 = m0 & 1023;
            const int bh = b_ * HH + h;
            f32x4 v = acc[mi][ni];
            if (proj == 2) {
                f16x4 pk;
#pragma unroll
                for (int r = 0; r < 4; ++r) pk[r] = (_Float16)(v[r] + bv_);
                *(f16x4*)(Vt + ((size_t)bh * 64 + dh) * SS + s0) = pk;
            } else {
                _Float16* dst = (proj == 0) ? Qb : Kb;
#pragma unroll
                for (int r = 0; r < 4; ++r)
                    dst[((size_t)bh * SS + (s0 + r)) * 64 + dh] =
                        (_Float16)(v[r] + bv_);
            }
        }
    }
}

// ---------------------------------------------------------------------------
// Kernel 3: flash attention.  [R5 changes: exp2-domain softmax (click/mask
//   pre-scaled by log2e), per-lane deferred l_run (cross-lane sum moved to
//   epilogue -> 2 fewer ds_permute shfls per u/ks), bare v_exp_f32 via
//   __builtin_amdgcn_exp2f.]
// ---------------------------------------------------------------------------
__global__ __launch_bounds__(256, 3) void attn_kernel(const _Float16* __restrict__ Qb,
                                                      const _Float16* __restrict__ Kb,
                                                      const _Float16* __restrict__ Vt,
                                                      const float* __restrict__ ckS,
                                                      const float* __restrict__ mkL,
                                                      float* __restrict__ out) {
    __shared__ __align__(16) _Float16 Ksh[2][64 * 64];
    __shared__ __align__(16) _Float16 Vsh[2][64 * 64];
    __shared__ __align__(16) _Float16 pT[4][2][16][40];

    const int tid = threadIdx.x;
    const int l = tid & 63, w = tid >> 6;
    const int lr = l & 15, lg = l >> 4;

    const int bid = blockIdx.x;
    const int nid = (bid & 7) * 96 + (bid >> 3);
    const int qt2 = nid & 7;
    const int bh  = nid >> 3;
    const int b_ = bh / HH, h = bh - b_ * HH;
    const int qb0 = qt2 * 128 + w * 16;

    const _Float16* Qp = Qb + (size_t)bh * (SS * 64);
    const _Float16* Kp = Kb + (size_t)bh * (SS * 64);
    const _Float16* Vp = Vt + (size_t)bh * (SS * 64);
    const float* ck = ckS + b_ * SS;
    const float* mk = mkL + b_ * SS;

    f16x8 qf[2][2];
#pragma unroll
    for (int u = 0; u < 2; ++u) {
        qf[u][0] = *(const f16x8*)(Qp + (size_t)(qb0 + u * 64 + lr) * 64 + lg * 8);
        qf[u][1] = *(const f16x8*)(Qp + (size_t)(qb0 + u * 64 + lr) * 64 + 32 + lg * 8);
    }

    const int srow = l >> 3;
    const int scb  = (l & 7) << 4;
    const int scol = (scb ^ (srow << 4)) >> 1;
    const _Float16* Kg = Kp + (size_t)(w * 16 + srow) * 64 + scol;
    const _Float16* Vg = Vp + (size_t)(w * 16 + srow) * SS + scol;

#pragma unroll
    for (int i = 0; i < 2; ++i) {
        GLOAD_LDS16(Kg + (size_t)(i * 8) * 64, &Ksh[0][w * 1024 + i * 512]);
        GLOAD_LDS16(Vg + (size_t)(i * 8) * SS, &Vsh[0][w * 1024 + i * 512]);
    }
    __syncthreads();

    f32x4 o[2][4] = {};
    float m_run[2] = {-3.0e38f, -3.0e38f};
    float l_run[2] = {0.f, 0.f};          // per-lane partial (reduced at end)
    const int sw = (lr & 7) << 4;

    for (int c = 0; c < 16; ++c) {
        const int cur = c & 1;
        if (c < 15) {
            const int nb = (c + 1) * 64;
#pragma unroll
            for (int i = 0; i < 2; ++i) {
                GLOAD_LDS16(Kg + (size_t)(nb + i * 8) * 64, &Ksh[cur ^ 1][w * 1024 + i * 512]);
                GLOAD_LDS16(Vg + nb + (size_t)(i * 8) * SS, &Vsh[cur ^ 1][w * 1024 + i * 512]);
            }
        }
        const _Float16* Ks = Ksh[cur];
        const _Float16* Vs = Vsh[cur];
        const int cb64 = c * 64;

#pragma unroll
        for (int ks = 0; ks < 2; ++ks) {
            // --- QK^T, K-frags shared across both q-sets
            f32x4 st[2][2];
            __builtin_amdgcn_s_setprio(1);
#pragma unroll
            for (int t = 0; t < 2; ++t) {
                const int row = (ks * 2 + t) * 16 + lr;
                const f16x8 kf0 = *(const f16x8*)(Ks + row * 64 + (((lg << 4) ^ sw) >> 1));
                const f16x8 kf1 = *(const f16x8*)(Ks + row * 64 + (((64 | (lg << 4)) ^ sw) >> 1));
#pragma unroll
                for (int u = 0; u < 2; ++u) {
                    f32x4 z = {};
                    z = __builtin_amdgcn_mfma_f32_16x16x32_f16(kf0, qf[u][0], z, 0, 0, 0);
                    st[u][t] = __builtin_amdgcn_mfma_f32_16x16x32_f16(kf1, qf[u][1], z, 0, 0, 0);
                }
            }
            __builtin_amdgcn_s_setprio(0);

            const int koff = cb64 + ks * 32 + lg * 4;
            const f32x4 ck0 = *(const f32x4*)(ck + koff);
            const f32x4 ck1 = *(const f32x4*)(ck + koff + 16);
            const f32x4 mk0 = *(const f32x4*)(mk + koff);
            const f32x4 mk1 = *(const f32x4*)(mk + koff + 16);

#pragma unroll
            for (int u = 0; u < 2; ++u) {
                // scores in log2 domain
                float s0[4], s1[4];
#pragma unroll
                for (int r = 0; r < 4; ++r) {
                    s0[r] = st[u][0][r] * ck0[r] + mk0[r];
                    s1[r] = st[u][1][r] * ck1[r] + mk1[r];
                }
                float tmax = fmaxf(fmaxf(fmaxf(s0[0], s0[1]), fmaxf(s0[2], s0[3])),
                                   fmaxf(fmaxf(s1[0], s1[1]), fmaxf(s1[2], s1[3])));
                tmax = fmaxf(tmax, __shfl_xor(tmax, 16));
                tmax = fmaxf(tmax, __shfl_xor(tmax, 32));

                // defer-max: threshold 8*log2e in log2 domain (P bound e^8)
                if (__any(tmax - m_run[u] > 11.5415603f)) {
                    const float m_new = fmaxf(m_run[u], tmax);
                    const float sc = __builtin_amdgcn_exp2f(m_run[u] - m_new);
                    l_run[u] *= sc;
#pragma unroll
                    for (int f = 0; f < 4; ++f)
#pragma unroll
                        for (int r = 0; r < 4; ++r) o[u][f][r] *= sc;
                    m_run[u] = m_new;
                }

                float psum = 0.f;
                f16x4 pk0, pk1;
#pragma unroll
                for (int r = 0; r < 4; ++r) {
                    const float p0 = __builtin_amdgcn_exp2f(s0[r] - m_run[u]);
                    const float p1 = __builtin_amdgcn_exp2f(s1[r] - m_run[u]);
                    psum += p0 + p1;
                    pk0[r] = (_Float16)p0;
                    pk1[r] = (_Float16)p1;
                }
                l_run[u] += psum;     // per-lane partial; no cross-lane here

                *(f16x4*)(&pT[w][u][lr][lg * 4]) = pk0;
                *(f16x4*)(&pT[w][u][lr][16 + lg * 4]) = pk1;
            }

            const f16x8 pb0 = *(const f16x8*)(&pT[w][0][lr][lg * 8]);
            const f16x8 pb1 = *(const f16x8*)(&pT[w][1][lr][lg * 8]);

            // --- PV: V-frag loaded once, feeds both q-sets
            __builtin_amdgcn_s_setprio(1);
#pragma unroll
            for (int f = 0; f < 4; ++f) {
                const int vrow = f * 16 + lr;
                const f16x8 vf = *(const f16x8*)(Vs + vrow * 64 +
                                                 ((((ks << 6) | (lg << 4)) ^ sw) >> 1));
                o[0][f] = __builtin_amdgcn_mfma_f32_16x16x32_f16(vf, pb0, o[0][f], 0, 0, 0);
                o[1][f] = __builtin_amdgcn_mfma_f32_16x16x32_f16(vf, pb1, o[1][f], 0, 0, 0);
            }
            __builtin_amdgcn_s_setprio(0);
        }
        __syncthreads();
    }

    // --- epilogue: cross-lane l_run reduction (once), normalize + store
#pragma unroll
    for (int u = 0; u < 2; ++u) {
        float lt = l_run[u];
        lt += __shfl_xor(lt, 16);
        lt += __shfl_xor(lt, 32);
        const float inv = 1.f / lt;
#pragma unroll
        for (int f = 0; f < 4; ++f) {
            f32x4 v = o[u][f];
#pragma unroll
            for (int r = 0; r < 4; ++r) v[r] *= inv;
            float* dst = out + ((size_t)(b_ * SS + qb0 + u * 64 + lr)) * DD +
                         h * 64 + f * 16 + lg * 4;
            *(f32x4*)dst = v;
        }
    }
}

// ---------------------------------------------------------------------------
// Launch
// ---------------------------------------------------------------------------
extern "C" void kernel_launch(void* const* d_in, const int* in_sizes, int n_in,
                              void* d_out, int out_size, void* d_ws, size_t ws_size,
                              hipStream_t stream) {
    const float* X     = (const float*)d_in[0];
    const float* mask  = (const float*)d_in[1];
    const float* click = (const float*)d_in[2];
    const float* Wq    = (const float*)d_in[3];
    const float* bq    = (const float*)d_in[4];
    const float* Wk    = (const float*)d_in[5];
    const float* bk    = (const float*)d_in[6];
    const float* Wv    = (const float*)d_in[7];
    const float* bv    = (const float*)d_in[8];
    float* out = (float*)d_out;

    char* ws = (char*)d_ws;
    _Float16* Xh  = (_Float16*)(ws);                  // 12,582,912 B
    _Float16* Wh  = (_Float16*)(ws + 12582912);       //  3,538,944 B
    float*    bia = (float*)   (ws + 16121856);       //      9,216 B
    float*    ckS = (float*)   (ws + 16131072);       //     32,768 B
    float*    mkL = (float*)   (ws + 16163840);       //     32,768 B
    _Float16* Qb  = (_Float16*)(ws + 16196608);       // 12,582,912 B
    _Float16* Kb  = (_Float16*)(ws + 28779520);       // 12,582,912 B
    _Float16* Vt  = (_Float16*)(ws + 41362432);       // 12,582,912 B

    prep_kernel<<<2048, 256, 0, stream>>>(X, Wq, Wk, Wv, bq, bk, bv, click, mask,
                                          Xh, Wh, bia, ckS, mkL);
    qkv_gemm<<<768, 256, 0, stream>>>(Xh, Wh, bia, Qb, Kb, Vt);
    attn_kernel<<<768, 256, 0, stream>>>(Qb, Kb, Vt, ckS, mkL, out);
}